// Round 1
// baseline (244.715 us; speedup 1.0000x reference)
//
#include <hip/hip_runtime.h>

// DigitCaps dynamic routing, fully fused.
// C=10 capsules, N=1152 nodes, DIN=8, DOUT=16, B=256, ITERS=3.
// One workgroup per (c,b). Priors (1152x16 f32 = 72KB) staged in LDS once,
// reused for all routing iterations. Logits are uniform over DOUT -> scalar a[n].

#define C_    10
#define N_    1152
#define DIN_  8
#define DOUT_ 16
#define B_    256
#define ITERS_ 3

#define THREADS 512
#define NWAVE   (THREADS/64)      // 8
#define NB      (THREADS/DOUT_)   // 32 node-groups
#define KITER   (N_/NB)           // 36 nodes per thread

__global__ __launch_bounds__(THREADS, 4)  // 4 waves/EU -> 2 blocks/CU (512-thr blocks)
void caps_route_kernel(const float* __restrict__ x,   // [B, N, DIN]
                       const float* __restrict__ W,   // [C, N, DIN, DOUT]
                       float* __restrict__ out)       // [C, B, 1, DOUT]
{
    __shared__ float p[N_ * DOUT_];        // 73728 B: priors for this (c,b)
    __shared__ float a[N_];                // 4608 B: routing logit per node
    __shared__ float red[NWAVE * DOUT_];   // cross-wave partials for s[o]
    __shared__ float red2[NWAVE];          // cross-wave partials for max/denom

    const int t    = threadIdx.x;
    const int o    = t & 15;       // output-channel owned by this thread
    const int nb   = t >> 4;       // node-group 0..31
    const int wave = t >> 6;       // 0..7
    const int lane = t & 63;

    const int bid = blockIdx.x;
    const int c   = bid >> 8;      // c-major: co-resident blocks share few W panels
    const int b   = bid & 255;

    const float* __restrict__ xb = x + (size_t)b * (N_ * DIN_);
    const float* __restrict__ Wc = W + (size_t)c * (N_ * DIN_ * DOUT_);

    // ---------------- priors -> LDS ----------------
    // p[n][o] = sum_i x[b,n,i] * W[c,n,i,o]
    #pragma unroll 2
    for (int k = 0; k < KITER; ++k) {
        const int n = nb + k * NB;
        const float4* xr = (const float4*)(xb + (size_t)n * DIN_);
        const float4 x0 = xr[0];
        const float4 x1 = xr[1];
        const float* wr = Wc + (size_t)n * (DIN_ * DOUT_) + o;  // stride DOUT_ per i
        float acc = x0.x * wr[0 * DOUT_] + x0.y * wr[1 * DOUT_]
                  + x0.z * wr[2 * DOUT_] + x0.w * wr[3 * DOUT_]
                  + x1.x * wr[4 * DOUT_] + x1.y * wr[5 * DOUT_]
                  + x1.z * wr[6 * DOUT_] + x1.w * wr[7 * DOUT_];
        p[n * DOUT_ + o] = acc;
        if (o == 0) a[n] = 0.0f;   // init logits
    }
    __syncthreads();

    // ---------------- routing ----------------
    float v_own = 0.0f;            // squashed output for this thread's o

    for (int it = 0; it < ITERS_; ++it) {
        float m = 0.0f;
        float inv_denom;

        if (it == 0) {
            inv_denom = 1.0f / (float)N_;   // softmax of zeros == uniform
        } else {
            // ---- max over a[n] ----
            float lm = -1e30f;
            for (int n = t; n < N_; n += THREADS) lm = fmaxf(lm, a[n]);
            #pragma unroll
            for (int off = 32; off; off >>= 1) lm = fmaxf(lm, __shfl_xor(lm, off));
            if (lane == 0) red2[wave] = lm;
            __syncthreads();
            float gm = red2[0];
            #pragma unroll
            for (int wv = 1; wv < NWAVE; ++wv) gm = fmaxf(gm, red2[wv]);
            m = gm;
            __syncthreads();   // red2 reuse

            // ---- denom = sum exp(a - m) ----
            float ls = 0.0f;
            for (int n = t; n < N_; n += THREADS) ls += expf(a[n] - m);
            #pragma unroll
            for (int off = 32; off; off >>= 1) ls += __shfl_xor(ls, off);
            if (lane == 0) red2[wave] = ls;
            __syncthreads();
            float denom = 0.0f;
            #pragma unroll
            for (int wv = 0; wv < NWAVE; ++wv) denom += red2[wv];
            inv_denom = 1.0f / denom;
        }

        // ---- s[o] = inv_denom * sum_n w_n * p[n][o] ----
        float part = 0.0f;
        for (int k = 0; k < KITER; ++k) {
            const int n = nb + k * NB;
            const float w = (it == 0) ? 1.0f : expf(a[n] - m);
            part += w * p[n * DOUT_ + o];
        }
        // reduce over nb sub-groups within the wave (lane bits 4,5)
        part += __shfl_xor(part, 16);
        part += __shfl_xor(part, 32);
        __syncthreads();                    // prior readers of red done
        if (lane < DOUT_) red[wave * DOUT_ + lane] = part;
        __syncthreads();
        float s = 0.0f;
        #pragma unroll
        for (int wv = 0; wv < NWAVE; ++wv) s += red[wv * DOUT_ + o];
        s *= inv_denom;

        // ---- squash along DOUT: v = s * sqrt(sq)/(1+sq) ----
        float sq = s * s;
        sq += __shfl_xor(sq, 1);
        sq += __shfl_xor(sq, 2);
        sq += __shfl_xor(sq, 4);
        sq += __shfl_xor(sq, 8);
        const float scale = sqrtf(sq) / (1.0f + sq);
        v_own = scale * s;

        // ---- logit update: a[n] += sum_o p[n][o]*v[o] ----
        if (it != ITERS_ - 1) {
            __syncthreads();   // all s-phase reads of a done before writes
            for (int k = 0; k < KITER; ++k) {
                const int n = nb + k * NB;
                float d = p[n * DOUT_ + o] * v_own;
                d += __shfl_xor(d, 1);
                d += __shfl_xor(d, 2);
                d += __shfl_xor(d, 4);
                d += __shfl_xor(d, 8);
                if (o == 0) a[n] += d;
            }
            __syncthreads();
        }
    }

    // ---------------- output ----------------
    if (t < DOUT_) {
        out[((size_t)c * B_ + b) * DOUT_ + t] = v_own;   // t == o here
    }
}

extern "C" void kernel_launch(void* const* d_in, const int* in_sizes, int n_in,
                              void* d_out, int out_size, void* d_ws, size_t ws_size,
                              hipStream_t stream) {
    const float* x = (const float*)d_in[0];   // [B, N, DIN]
    const float* W = (const float*)d_in[1];   // [C, N, DIN, DOUT]
    float* out = (float*)d_out;               // [C, B, 1, DOUT]
    (void)in_sizes; (void)n_in; (void)out_size; (void)d_ws; (void)ws_size;

    caps_route_kernel<<<dim3(C_ * B_), dim3(THREADS), 0, stream>>>(x, W, out);
}

// Round 2
// 132.545 us; speedup vs baseline: 1.8463x; 1.8463x over previous
//
#include <hip/hip_runtime.h>

// DigitCaps dynamic routing, fully fused. C=10, N=1152, DIN=8, DOUT=16, B=256, ITERS=3.
// One workgroup per (c,b). Priors staged once in LDS (72KB), logits live in
// registers (node-owned), exp computed once per node into e[] (LDS), s-phase
// o-owned with broadcast e reads, logit update node-owned with float4 p reads.

#define C_    10
#define N_    1152
#define DIN_  8
#define DOUT_ 16
#define B_    256
#define ITERS_ 3

#define THREADS 512
#define NWAVE   (THREADS/64)      // 8

static __device__ __forceinline__ float dot4(float4 a, float4 b) {
    return a.x*b.x + a.y*b.y + a.z*b.z + a.w*b.w;
}
#define FMA4(acc, s, v) { acc.x += (s)*(v).x; acc.y += (s)*(v).y; acc.z += (s)*(v).z; acc.w += (s)*(v).w; }

__global__ __launch_bounds__(THREADS, 4)  // cap VGPR<=128 -> 2 blocks/CU (LDS-bound anyway)
void caps_route_kernel(const float* __restrict__ x,   // [B, N, DIN]
                       const float* __restrict__ W,   // [C, N, DIN, DOUT]
                       float* __restrict__ out)       // [C, B, 1, DOUT]
{
    __shared__ float p[N_ * DOUT_];        // 73728 B priors
    __shared__ float e[N_];                // 4608 B  softmax numerators
    __shared__ float redm[NWAVE];          // wave maxes
    __shared__ float reds[NWAVE];          // wave sums
    __shared__ float sred[NWAVE * DOUT_];  // cross-wave s partials
    __shared__ float vbuf[DOUT_];          // broadcast v

    const int t    = threadIdx.x;
    const int o    = t & 15;
    const int nb   = t >> 4;
    const int wave = t >> 6;
    const int lane = t & 63;

    const int bid = blockIdx.x;
    const int c   = bid >> 8;
    const int b   = bid & 255;

    const float*  xb  = x + (size_t)b * (N_ * DIN_);
    const float4* Wc4 = (const float4*)(W + (size_t)c * (N_ * DIN_ * DOUT_));
    float4* p4 = (float4*)p;

    // ---------------- priors -> LDS (o-quad mapping) ----------------
    // thread (ng, oq): p[n][4oq..4oq+3] for n = ng + 128k
    {
        const int oq = t & 3;
        const int ng = t >> 2;
        #pragma unroll 2
        for (int k = 0; k < 9; ++k) {
            const int n = ng + (k << 7);
            const float4* xr = (const float4*)(xb + n * DIN_);
            const float4 x0 = xr[0];
            const float4 x1 = xr[1];
            const float4* wr = Wc4 + n * 32 + oq;   // stride 4 float4 per i
            float4 acc = make_float4(0.f, 0.f, 0.f, 0.f);
            FMA4(acc, x0.x, wr[0]);
            FMA4(acc, x0.y, wr[4]);
            FMA4(acc, x0.z, wr[8]);
            FMA4(acc, x0.w, wr[12]);
            FMA4(acc, x1.x, wr[16]);
            FMA4(acc, x1.y, wr[20]);
            FMA4(acc, x1.z, wr[24]);
            FMA4(acc, x1.w, wr[28]);
            p4[n * 4 + oq] = acc;
        }
    }
    __syncthreads();

    // ---------------- routing ----------------
    // logits for owned nodes {t, t+512, t+1024(if t<128)} live in registers
    float l0 = 0.f, l1 = 0.f, l2 = 0.f;
    const bool has3 = (t < (N_ - 2 * THREADS));   // t < 128

    float v_own = 0.f;

    for (int it = 0; it < ITERS_; ++it) {
        float inv_denom;

        if (it == 0) {
            inv_denom = 1.0f / (float)N_;          // softmax of zeros = uniform
        } else {
            // ---- block max over register logits ----
            float lm = fmaxf(l0, l1);
            if (has3) lm = fmaxf(lm, l2);
            #pragma unroll
            for (int off = 32; off; off >>= 1) lm = fmaxf(lm, __shfl_xor(lm, off));
            if (lane == 0) redm[wave] = lm;
            __syncthreads();
            float m = redm[0];
            #pragma unroll
            for (int wv = 1; wv < NWAVE; ++wv) m = fmaxf(m, redm[wv]);

            // ---- e[n] = exp(l - m), once per node; denom = sum ----
            const float e0 = expf(l0 - m);
            const float e1 = expf(l1 - m);
            const float e2 = has3 ? expf(l2 - m) : 0.f;
            e[t] = e0;
            e[t + THREADS] = e1;
            if (has3) e[t + 2 * THREADS] = e2;
            float ls = e0 + e1 + e2;
            #pragma unroll
            for (int off = 32; off; off >>= 1) ls += __shfl_xor(ls, off);
            if (lane == 0) reds[wave] = ls;
            __syncthreads();                        // e[] + reds ready
            float denom = 0.f;
            #pragma unroll
            for (int wv = 0; wv < NWAVE; ++wv) denom += reds[wv];
            inv_denom = 1.0f / denom;
        }

        // ---- s[o] = inv_denom * sum_n e[n] * p[n][o]  (o-owned) ----
        float part = 0.f;
        if (it == 0) {
            #pragma unroll 6
            for (int k = 0; k < 36; ++k) {
                const int n = nb + (k << 5);
                part += p[n * DOUT_ + o];
            }
        } else {
            #pragma unroll 6
            for (int k = 0; k < 36; ++k) {
                const int n = nb + (k << 5);
                part += e[n] * p[n * DOUT_ + o];
            }
        }
        part += __shfl_xor(part, 16);
        part += __shfl_xor(part, 32);
        if (lane < DOUT_) sred[wave * DOUT_ + lane] = part;
        __syncthreads();
        float s = 0.f;
        #pragma unroll
        for (int wv = 0; wv < NWAVE; ++wv) s += sred[wv * DOUT_ + o];
        s *= inv_denom;

        // ---- squash over DOUT ----
        float sq = s * s;
        sq += __shfl_xor(sq, 1);
        sq += __shfl_xor(sq, 2);
        sq += __shfl_xor(sq, 4);
        sq += __shfl_xor(sq, 8);
        const float scale = sqrtf(sq) / (1.0f + sq);
        v_own = scale * s;

        // ---- logit update (node-owned, float4, no shuffles) ----
        if (it != ITERS_ - 1) {
            if (t < DOUT_) vbuf[t] = v_own;
            __syncthreads();                        // vbuf ready; also fences sred/e reads
            const float4 va = ((const float4*)vbuf)[0];
            const float4 vb = ((const float4*)vbuf)[1];
            const float4 vc = ((const float4*)vbuf)[2];
            const float4 vd = ((const float4*)vbuf)[3];
            {
                const float4* pr = p4 + (size_t)t * 4;
                l0 += dot4(pr[0], va) + dot4(pr[1], vb) + dot4(pr[2], vc) + dot4(pr[3], vd);
            }
            {
                const float4* pr = p4 + (size_t)(t + THREADS) * 4;
                l1 += dot4(pr[0], va) + dot4(pr[1], vb) + dot4(pr[2], vc) + dot4(pr[3], vd);
            }
            if (has3) {
                const float4* pr = p4 + (size_t)(t + 2 * THREADS) * 4;
                l2 += dot4(pr[0], va) + dot4(pr[1], vb) + dot4(pr[2], vc) + dot4(pr[3], vd);
            }
            // no barrier needed: next phase writes disjoint LDS (redm/reds/e),
            // and its own barriers precede any cross-thread reads.
        }
    }

    // ---------------- output ----------------
    if (t < DOUT_) {
        out[((size_t)c * B_ + b) * DOUT_ + t] = v_own;   // t == o
    }
}

extern "C" void kernel_launch(void* const* d_in, const int* in_sizes, int n_in,
                              void* d_out, int out_size, void* d_ws, size_t ws_size,
                              hipStream_t stream) {
    const float* x = (const float*)d_in[0];   // [B, N, DIN]
    const float* W = (const float*)d_in[1];   // [C, N, DIN, DOUT]
    float* out = (float*)d_out;               // [C, B, 1, DOUT]
    (void)in_sizes; (void)n_in; (void)out_size; (void)d_ws; (void)ws_size;

    caps_route_kernel<<<dim3(C_ * B_), dim3(THREADS), 0, stream>>>(x, W, out);
}